// Round 5
// baseline (778.582 us; speedup 1.0000x reference)
//
#include <hip/hip_runtime.h>

// GlobalFusion R5:
//  - k_merge1: conflict-free LDS staging (gather 8ch/px -> ushort8 write along c)
//  - k_dwm2:  fused depthwise3x3+GELU -> 1x1 GEMM + bias + residual (one row/block)
//  - k_apool: fused alpha-conv3x3 -> softmax(V) -> weighted pool (one row/block)
// fp32 in/out; bf16 intermediates; bf16 MFMA for GEMMs.

#define DEV static __device__ __forceinline__

typedef __attribute__((ext_vector_type(8))) short short8x;
typedef __attribute__((ext_vector_type(8))) unsigned short ushort8x;
typedef __attribute__((ext_vector_type(4))) float f32x4;

constexpr int Bc = 2, Vc = 6, Cc = 128, Hc = 128, Wc = 128;
constexpr int Nc = Bc * Vc;      // 12
constexpr int Pc = Hc * Wc;      // 16384
constexpr int NPX = Nc * Pc;     // 196608

DEV float us2f(unsigned short u) {
  return __builtin_bit_cast(float, (unsigned int)u << 16);
}
DEV unsigned short f2us(float f) {
  unsigned int i = __builtin_bit_cast(unsigned int, f);
  unsigned int r = i + 0x7FFFu + ((i >> 16) & 1u);   // RNE
  return (unsigned short)(r >> 16);
}
DEV float geluf(float x) { return x * 0.5f * (1.f + erff(x * 0.70710678118654752f)); }
DEV float sigm(float x) { return 1.f / (1.f + __expf(-x)); }

// ---------------- weight prep: fp32 -> bf16 (+ GRU row interleave) ----------------
__global__ __launch_bounds__(256) void k_prepw(
    const float* __restrict__ w1, const float* __restrict__ w2,
    const float* __restrict__ wu, const float* __restrict__ gw,
    const float* __restrict__ gbw, unsigned short* __restrict__ wbf) {
  int idx = blockIdx.x * 256 + threadIdx.x;
  float v;
  if (idx < 32768) {
    v = w1[idx];
  } else if (idx < 49152) {
    v = w2[idx - 32768];
  } else if (idx < 65536) {
    v = wu[idx - 49152];
  } else {
    int i = (idx < 98304) ? (idx - 65536) : (idx - 98304);
    int np = i >> 7, k = i & 127;
    int j = np >> 5, s = np & 31;
    int src = (s < 16) ? (16 * j + s) : (128 + 16 * j + (s - 16));
    const float* w = (idx < 98304) ? gw : gbw;
    v = w[src * 128 + k];
  }
  wbf[idx] = f2us(v);
}

// ---------------- K1: merge 1x1 conv 256->128 + GELU (MFMA) ----------------
// Conflict-free staging: thread owns one px, gathers 8 ch via strided dwords
// (lane-coalesced along px), writes one ushort8 along c.
__global__ __launch_bounds__(256) void k_merge1(
    const float* __restrict__ feats, const float* __restrict__ prj,
    const unsigned short* __restrict__ w1b, const float* __restrict__ b1,
    unsigned short* __restrict__ m1, unsigned short* __restrict__ fres) {
  __shared__ unsigned short sA[128][72];
  __shared__ unsigned short sB[128][72];
  const int t = threadIdx.x;
  const int wave = t >> 6, lane = t & 63, quad = lane >> 4, lr = lane & 15;
  const int wm = (wave >> 1) * 64, wn = (wave & 1) * 64;
  const int mb = blockIdx.x;
  const size_t m0 = (size_t)mb * 128;
  const int n = mb >> 7;
  const int p0 = (mb & 127) << 7;
  const int px = t & 127, halfc = t >> 7;
  f32x4 acc[4][4];
#pragma unroll
  for (int i = 0; i < 4; i++)
#pragma unroll
    for (int j = 0; j < 4; j++) acc[i][j] = (f32x4){0.f, 0.f, 0.f, 0.f};

  for (int k0 = 0; k0 < 256; k0 += 64) {
    // stage A: 128 px x 64 c slice, transposed on the fly
#pragma unroll
    for (int g = 0; g < 4; ++g) {
      int c0 = halfc * 32 + g * 8;
      int ch = k0 + c0;
      const float* src = (ch < 128)
          ? (feats + ((size_t)(n * 128 + ch)) * Pc + p0 + px)
          : (prj + ((size_t)(n * 128 + (ch - 128))) * Pc + p0 + px);
      ushort8x pk;
#pragma unroll
      for (int j = 0; j < 8; ++j) pk[j] = f2us(src[(size_t)j * Pc]);
      *(ushort8x*)&sA[px][c0] = pk;
    }
    // stage B: weights [128 out][256 in] slice
    for (int u = t; u < 1024; u += 256) {
      int row = u >> 3, seg = u & 7;
      *(uint4*)&sB[row][seg * 8] =
          *(const uint4*)(w1b + (size_t)row * 256 + k0 + seg * 8);
    }
    __syncthreads();
#pragma unroll
    for (int ks = 0; ks < 2; ++ks) {
      const int kk = ks * 32 + quad * 8;
      short8x a[4], bf[4];
#pragma unroll
      for (int i = 0; i < 4; i++)
        a[i] = *reinterpret_cast<const short8x*>(&sA[wm + i * 16 + lr][kk]);
#pragma unroll
      for (int j = 0; j < 4; j++)
        bf[j] = *reinterpret_cast<const short8x*>(&sB[wn + j * 16 + lr][kk]);
#pragma unroll
      for (int i = 0; i < 4; i++)
#pragma unroll
        for (int j = 0; j < 4; j++)
          acc[i][j] = __builtin_amdgcn_mfma_f32_16x16x32_bf16(a[i], bf[j], acc[i][j], 0, 0, 0);
    }
    if (k0 < 128) {   // feats slice passthrough -> fres
      for (int u = t; u < 1024; u += 256) {
        int row = u >> 3, seg = u & 7;
        *(uint4*)(fres + (m0 + row) * 128 + k0 + seg * 8) =
            *(const uint4*)&sA[row][seg * 8];
      }
    }
    __syncthreads();
  }
#pragma unroll
  for (int i = 0; i < 4; i++)
#pragma unroll
    for (int r = 0; r < 4; r++) {
      size_t row = m0 + wm + i * 16 + quad * 4 + r;
#pragma unroll
      for (int j = 0; j < 4; j++) {
        int c = wn + j * 16 + lr;
        m1[row * 128 + c] = f2us(geluf(acc[i][j][r] + b1[c]));
      }
    }
}

// ---------------- K2: fused dw3x3+GELU -> 1x1 GEMM +bias+residual ----------------
// Block = one image row (n, y): 128 px. dw in registers from global m1,
// results staged to LDS [128px][128c], then MFMA with w2, epilogue residual.
__global__ __launch_bounds__(256) void k_dwm2(
    const unsigned short* __restrict__ m1, const unsigned short* __restrict__ w2b,
    const float* __restrict__ b2, const float* __restrict__ wd,
    const float* __restrict__ bd, const unsigned short* __restrict__ fres,
    unsigned short* __restrict__ X1) {
  __shared__ unsigned short sD[128][136];
  __shared__ unsigned short sB[128][136];
  __shared__ float swd[Cc * 9];
  __shared__ float sbd[Cc];
  const int t = threadIdx.x;
  const int wave = t >> 6, lane = t & 63, quad = lane >> 4, lr = lane & 15;
  const int wm = (wave >> 1) * 64, wn = (wave & 1) * 64;
  const int blk = blockIdx.x;
  const int n = blk >> 7, y = blk & 127;
  const size_t m0 = (size_t)blk * 128;   // = n*Pc + y*128
  const int x = t & 127, halfc = t >> 7;

  for (int i = t; i < Cc * 9; i += 256) swd[i] = wd[i];
  if (t < Cc) sbd[t] = bd[t];
  for (int u = t; u < 2048; u += 256) {
    int row = u >> 4, seg = u & 15;
    *(uint4*)&sB[row][seg * 8] = *(const uint4*)(w2b + (size_t)row * 128 + seg * 8);
  }
  __syncthreads();

  // depthwise 3x3 + gelu -> sD
#pragma unroll
  for (int g = 0; g < 8; ++g) {
    const int c0 = halfc * 64 + g * 8;
    float acc[8];
#pragma unroll
    for (int j = 0; j < 8; ++j) acc[j] = sbd[c0 + j];
#pragma unroll
    for (int dy = 0; dy < 3; ++dy) {
      int yy = y + dy - 1;
      if (yy < 0 || yy >= Hc) continue;
#pragma unroll
      for (int dx = 0; dx < 3; ++dx) {
        int xx = x + dx - 1;
        if (xx >= 0 && xx < Wc) {
          ushort8x v = *(const ushort8x*)(m1 + ((size_t)(n * Pc + yy * Wc + xx)) * 128 + c0);
#pragma unroll
          for (int j = 0; j < 8; ++j)
            acc[j] += us2f(v[j]) * swd[(c0 + j) * 9 + dy * 3 + dx];
        }
      }
    }
    ushort8x pk;
#pragma unroll
    for (int j = 0; j < 8; ++j) pk[j] = f2us(geluf(acc[j]));
    *(ushort8x*)&sD[x][c0] = pk;
  }
  __syncthreads();

  f32x4 acc[4][4];
#pragma unroll
  for (int i = 0; i < 4; i++)
#pragma unroll
    for (int j = 0; j < 4; j++) acc[i][j] = (f32x4){0.f, 0.f, 0.f, 0.f};
#pragma unroll
  for (int ks = 0; ks < 4; ++ks) {
    const int kk = ks * 32 + quad * 8;
    short8x a[4], bf[4];
#pragma unroll
    for (int i = 0; i < 4; i++)
      a[i] = *reinterpret_cast<const short8x*>(&sD[wm + i * 16 + lr][kk]);
#pragma unroll
    for (int j = 0; j < 4; j++)
      bf[j] = *reinterpret_cast<const short8x*>(&sB[wn + j * 16 + lr][kk]);
#pragma unroll
    for (int i = 0; i < 4; i++)
#pragma unroll
      for (int j = 0; j < 4; j++)
        acc[i][j] = __builtin_amdgcn_mfma_f32_16x16x32_bf16(a[i], bf[j], acc[i][j], 0, 0, 0);
  }
#pragma unroll
  for (int i = 0; i < 4; i++)
#pragma unroll
    for (int r = 0; r < 4; r++) {
      size_t row = m0 + wm + i * 16 + quad * 4 + r;
#pragma unroll
      for (int j = 0; j < 4; j++) {
        int c = wn + j * 16 + lr;
        float v = acc[i][j][r] + b2[c] + us2f(fres[row * 128 + c]);
        X1[row * 128 + c] = f2us(v);
      }
    }
}

// ---------------- K4: fused bidirectional minGRU (MFMA + scans) ----------------
__global__ __launch_bounds__(256) void k_gru(
    const unsigned short* __restrict__ X1, const unsigned short* __restrict__ Wg,
    const unsigned short* __restrict__ Wb, unsigned short* __restrict__ F2) {
  __shared__ unsigned short sA[96][72];
  __shared__ unsigned short sB[256][72];
  __shared__ unsigned short sH[96][136];
  const int t = threadIdx.x;
  const int wave = t >> 6, lane = t & 63, quad = lane >> 4, lr = lane & 15;
  const int blk = blockIdx.x;
  const int b = blk >> 10, p0 = (blk & 1023) << 4;
  f32x4 acc[6][4];
#pragma unroll
  for (int v = 0; v < 6; v++)
#pragma unroll
    for (int j = 0; j < 4; j++) acc[v][j] = (f32x4){0.f, 0.f, 0.f, 0.f};

  for (int k0 = 0; k0 < 128; k0 += 64) {
    for (int u = t; u < 768; u += 256) {
      int r = u >> 3, seg = u & 7;
      int v = r >> 4, ps = r & 15;
      *(uint4*)&sA[r][seg * 8] =
          *(const uint4*)(X1 + ((size_t)((b * 6 + v) * Pc + p0 + ps)) * 128 + k0 + seg * 8);
    }
    for (int u = t; u < 2048; u += 256) {
      int rw = u >> 3, seg = u & 7;
      *(uint4*)&sB[rw][seg * 8] = *(const uint4*)(Wg + (size_t)rw * 128 + k0 + seg * 8);
    }
    __syncthreads();
#pragma unroll
    for (int ks = 0; ks < 2; ++ks) {
      const int kk = ks * 32 + quad * 8;
      short8x a[6], bf[4];
#pragma unroll
      for (int v = 0; v < 6; v++)
        a[v] = *reinterpret_cast<const short8x*>(&sA[v * 16 + lr][kk]);
#pragma unroll
      for (int j = 0; j < 4; j++)
        bf[j] = *reinterpret_cast<const short8x*>(&sB[wave * 64 + j * 16 + lr][kk]);
#pragma unroll
      for (int v = 0; v < 6; v++)
#pragma unroll
        for (int j = 0; j < 4; j++)
          acc[v][j] = __builtin_amdgcn_mfma_f32_16x16x32_bf16(a[v], bf[j], acc[v][j], 0, 0, 0);
    }
    __syncthreads();
  }
#pragma unroll
  for (int q = 0; q < 2; q++)
#pragma unroll
    for (int r = 0; r < 4; r++) {
      float h = 0.f;
#pragma unroll
      for (int v = 0; v < 6; v++) {
        float hid = acc[v][2 * q][r], gat = acc[v][2 * q + 1][r];
        float z = sigm(gat);
        float ht = (hid >= 0.f) ? (hid + 0.5f) : sigm(hid);
        h = (1.f - z) * h + z * ht;
        sH[v * 16 + quad * 4 + r][wave * 32 + q * 16 + lr] = f2us(h);
      }
    }
  __syncthreads();

#pragma unroll
  for (int v = 0; v < 6; v++)
#pragma unroll
    for (int j = 0; j < 4; j++) acc[v][j] = (f32x4){0.f, 0.f, 0.f, 0.f};
  for (int k0 = 0; k0 < 128; k0 += 64) {
    for (int u = t; u < 2048; u += 256) {
      int rw = u >> 3, seg = u & 7;
      *(uint4*)&sB[rw][seg * 8] = *(const uint4*)(Wb + (size_t)rw * 128 + k0 + seg * 8);
    }
    __syncthreads();
#pragma unroll
    for (int ks = 0; ks < 2; ++ks) {
      const int kk = ks * 32 + quad * 8;
      short8x a[6], bf[4];
#pragma unroll
      for (int v = 0; v < 6; v++)
        a[v] = *reinterpret_cast<const short8x*>(&sH[v * 16 + lr][k0 + kk]);
#pragma unroll
      for (int j = 0; j < 4; j++)
        bf[j] = *reinterpret_cast<const short8x*>(&sB[wave * 64 + j * 16 + lr][kk]);
#pragma unroll
      for (int v = 0; v < 6; v++)
#pragma unroll
        for (int j = 0; j < 4; j++)
          acc[v][j] = __builtin_amdgcn_mfma_f32_16x16x32_bf16(a[v], bf[j], acc[v][j], 0, 0, 0);
    }
    __syncthreads();
  }
#pragma unroll
  for (int q = 0; q < 2; q++)
#pragma unroll
    for (int r = 0; r < 4; r++) {
      float h = 0.f;
#pragma unroll
      for (int v = 0; v < 6; v++) {
        float hid = acc[v][2 * q][r], gat = acc[v][2 * q + 1][r];
        float z = sigm(gat);
        float ht = (hid >= 0.f) ? (hid + 0.5f) : sigm(hid);
        h = (1.f - z) * h + z * ht;
        F2[((size_t)((b * 6 + v) * Pc + p0 + quad * 4 + r)) * 128 + wave * 32 + q * 16 + lr] =
            f2us(h);
      }
    }
}

// ---------------- K5: fused alpha 3x3 conv -> softmax(V) -> pool ----------------
// Block = (b, y): 128 px row across all 6 views.
__global__ __launch_bounds__(256) void k_apool(
    const unsigned short* __restrict__ F2, const float* __restrict__ wa,
    unsigned short* __restrict__ P2) {
  __shared__ float swa[Cc * 9];
  __shared__ float sAl[128][6];
  const int t = threadIdx.x;
  const int blk = blockIdx.x;
  const int b = blk >> 7, y = blk & 127;
  const int x = t & 127;
  for (int i = t; i < Cc * 9; i += 256) swa[i] = wa[i];
  __syncthreads();

  // phase 1: alpha for 3 views per thread (vh selects view group)
  const int vh = t >> 7;
#pragma unroll
  for (int vi = 0; vi < 3; ++vi) {
    const int v = vh * 3 + vi;
    const int nn = b * 6 + v;
    float a = 0.f;
#pragma unroll
    for (int dy = 0; dy < 3; ++dy) {
      int yy = y + dy - 1;
      if (yy < 0 || yy >= Hc) continue;
#pragma unroll
      for (int dx = 0; dx < 3; ++dx) {
        int xx = x + dx - 1;
        if (xx >= 0 && xx < Wc) {
          const unsigned short* rowp = F2 + ((size_t)(nn * Pc + yy * Wc + xx)) * 128;
#pragma unroll
          for (int g = 0; g < 16; ++g) {
            ushort8x val = *(const ushort8x*)(rowp + g * 8);
#pragma unroll
            for (int j = 0; j < 8; ++j)
              a += us2f(val[j]) * swa[(g * 8 + j) * 9 + dy * 3 + dx];
          }
        }
      }
    }
    sAl[x][v] = a;   // +ba cancels in softmax
  }
  __syncthreads();

  // phase 2: softmax over V + weighted pool (thread = px x 64-ch half)
  const int halfc = t >> 7;
  float av[6];
  float mx = -1e30f;
#pragma unroll
  for (int v = 0; v < 6; ++v) { av[v] = sAl[x][v]; mx = fmaxf(mx, av[v]); }
  float s = 0.f;
#pragma unroll
  for (int v = 0; v < 6; ++v) { av[v] = __expf(av[v] - mx); s += av[v]; }
  const float inv = 1.f / s;
#pragma unroll
  for (int v = 0; v < 6; ++v) av[v] *= inv;
  const size_t prow = (size_t)(b * Pc + y * Wc + x);
#pragma unroll
  for (int g = 0; g < 8; ++g) {
    const int c0 = halfc * 64 + g * 8;
    float acc[8];
#pragma unroll
    for (int j = 0; j < 8; ++j) acc[j] = 0.f;
#pragma unroll
    for (int v = 0; v < 6; ++v) {
      ushort8x vv = *(const ushort8x*)(F2 + ((size_t)((b * 6 + v) * Pc + y * Wc + x)) * 128 + c0);
#pragma unroll
      for (int j = 0; j < 8; ++j) acc[j] += us2f(vv[j]) * av[v];
    }
    ushort8x pk;
#pragma unroll
    for (int j = 0; j < 8; ++j) pk[j] = f2us(acc[j]);
    *(ushort8x*)(P2 + prow * 128 + c0) = pk;
  }
}

// ---------------- K7: up 1x1 conv + pixel_shuffle(4) (MFMA) ----------------
__global__ __launch_bounds__(256) void k_up(
    const unsigned short* __restrict__ A, const unsigned short* __restrict__ wub,
    const float* __restrict__ bu, unsigned short* __restrict__ us_) {
  __shared__ unsigned short sA[128][72];
  __shared__ unsigned short sB[128][72];
  const int t = threadIdx.x;
  const int wave = t >> 6, lane = t & 63, quad = lane >> 4, lr = lane & 15;
  const int wm = (wave >> 1) * 64, wn = (wave & 1) * 64;
  const size_t m0 = (size_t)blockIdx.x * 128;
  f32x4 acc[4][4];
#pragma unroll
  for (int i = 0; i < 4; i++)
#pragma unroll
    for (int j = 0; j < 4; j++) acc[i][j] = (f32x4){0.f, 0.f, 0.f, 0.f};

  for (int k0 = 0; k0 < 128; k0 += 64) {
    for (int u = t; u < 1024; u += 256) {
      int row = u >> 3, seg = u & 7;
      *(uint4*)&sA[row][seg * 8] =
          *(const uint4*)(A + (m0 + row) * 128 + k0 + seg * 8);
    }
    for (int u = t; u < 1024; u += 256) {
      int row = u >> 3, seg = u & 7;
      *(uint4*)&sB[row][seg * 8] =
          *(const uint4*)(wub + (size_t)row * 128 + k0 + seg * 8);
    }
    __syncthreads();
#pragma unroll
    for (int ks = 0; ks < 2; ++ks) {
      const int kk = ks * 32 + quad * 8;
      short8x a[4], bf[4];
#pragma unroll
      for (int i = 0; i < 4; i++)
        a[i] = *reinterpret_cast<const short8x*>(&sA[wm + i * 16 + lr][kk]);
#pragma unroll
      for (int j = 0; j < 4; j++)
        bf[j] = *reinterpret_cast<const short8x*>(&sB[wn + j * 16 + lr][kk]);
#pragma unroll
      for (int i = 0; i < 4; i++)
#pragma unroll
        for (int j = 0; j < 4; j++)
          acc[i][j] = __builtin_amdgcn_mfma_f32_16x16x32_bf16(a[i], bf[j], acc[i][j], 0, 0, 0);
    }
    __syncthreads();
  }
#pragma unroll
  for (int i = 0; i < 4; i++)
#pragma unroll
    for (int r = 0; r < 4; r++) {
      size_t row = m0 + wm + i * 16 + quad * 4 + r;
      int b = (int)(row >> 14), p = (int)(row & (Pc - 1));
      int y = p >> 7, x = p & 127;
#pragma unroll
      for (int j = 0; j < 4; j++) {
        int c = wn + j * 16 + lr;
        float v = acc[i][j][r] + bu[c];
        int co = c >> 4, r1 = (c >> 2) & 3, r2 = c & 3;
        us_[(((size_t)b * 8 + co) * 512 + (y * 4 + r1)) * 512 + (x * 4 + r2)] = f2us(v);
      }
    }
}

// ---------------- K8: 3x3 conv 8->3 on 512x512, fp32 output ----------------
__global__ __launch_bounds__(256) void k_outc(
    const unsigned short* __restrict__ us_, const float* __restrict__ wo,
    const float* __restrict__ bo, float* __restrict__ out) {
  __shared__ float w[3 * 8 * 9];
  for (int i = threadIdx.x; i < 216; i += 256) w[i] = wo[i];
  __syncthreads();
  int i = blockIdx.x;
  const int xh = i & 1; i >>= 1;
  const int Y = i & 511; i >>= 9;
  const int o = i % 3;
  const int b = i / 3;
  const int X = xh * 256 + threadIdx.x;
  float acc = bo[o];
  for (int ci = 0; ci < 8; ++ci) {
    const unsigned short* pl = us_ + ((size_t)b * 8 + ci) * 512 * 512;
    const float* wc = w + o * 72 + ci * 9;
#pragma unroll
    for (int dy = 0; dy < 3; ++dy) {
      int YY = Y + dy - 1;
      if (YY < 0 || YY >= 512) continue;
#pragma unroll
      for (int dx = 0; dx < 3; ++dx) {
        int XX = X + dx - 1;
        if (XX < 0 || XX >= 512) continue;
        acc += wc[dy * 3 + dx] * us2f(pl[(size_t)YY * 512 + XX]);
      }
    }
  }
  out[(((size_t)b * 3 + o) * 512 + Y) * 512 + X] = acc;
}

// ---------------- launcher ----------------
extern "C" void kernel_launch(void* const* d_in, const int* in_sizes, int n_in,
                              void* d_out, int out_size, void* d_ws, size_t ws_size,
                              hipStream_t stream) {
  const float* feats = (const float*)d_in[0];
  const float* prj = (const float*)d_in[1];
  const float* w1 = (const float*)d_in[2];
  const float* b1 = (const float*)d_in[3];
  const float* wd = (const float*)d_in[4];
  const float* bd = (const float*)d_in[5];
  const float* w2 = (const float*)d_in[6];
  const float* b2 = (const float*)d_in[7];
  const float* gw = (const float*)d_in[8];
  const float* gbw = (const float*)d_in[9];
  const float* wa = (const float*)d_in[10];
  const float* bu = (const float*)d_in[13];
  const float* wu = (const float*)d_in[12];
  const float* wo = (const float*)d_in[14];
  const float* bo = (const float*)d_in[15];
  float* out = (float*)d_out;

  char* ws = (char*)d_ws;
  unsigned short* buf0 = (unsigned short*)(ws + 0);            // m1, then F2
  unsigned short* buf1 = (unsigned short*)(ws + 50331648);     // X1
  unsigned short* fres = (unsigned short*)(ws + 100663296);    // bf16 feats
  unsigned short* P2 = (unsigned short*)(ws + 150994944);      // 8,388,608
  unsigned short* ushuf = (unsigned short*)(ws + 159383552);   // 8,388,608
  unsigned short* wbf = (unsigned short*)(ws + 167772160);     // 262,144

  const unsigned short* w1b = wbf;
  const unsigned short* w2b = wbf + 32768;
  const unsigned short* wub = wbf + 49152;
  const unsigned short* wgi = wbf + 65536;
  const unsigned short* wgbi = wbf + 98304;

  dim3 blk(256);
  k_prepw<<<dim3(512), blk, 0, stream>>>(w1, w2, wu, gw, gbw, wbf);
  k_merge1<<<dim3(NPX / 128), blk, 0, stream>>>(feats, prj, w1b, b1, buf0, fres);
  k_dwm2<<<dim3(NPX / 128), blk, 0, stream>>>(buf0, w2b, b2, wd, bd, fres, buf1);
  k_gru<<<dim3(Bc * (Pc / 16)), blk, 0, stream>>>(buf1, wgi, wgbi, buf0);
  k_apool<<<dim3(Bc * Hc), blk, 0, stream>>>(buf0, wa, P2);
  k_up<<<dim3(Bc * Pc / 128), blk, 0, stream>>>(P2, wub, bu, ushuf);
  k_outc<<<dim3(2 * 3 * 512 * 2), blk, 0, stream>>>(ushuf, wo, bo, out);

  (void)in_sizes; (void)n_in; (void)out_size; (void)ws_size;
}